// Round 1
// baseline (225.305 us; speedup 1.0000x reference)
//
#include <hip/hip_runtime.h>
#include <math.h>

#define B_SZ 4096
#define N_PTS 2048
#define BLOCK 256
#define WPB (BLOCK / 64)   // waves per block = 4, one batch element per wave

__device__ __forceinline__ float huber1(float a) {
    // a >= 0, delta = 1: 0.5*q*q + (a - q), q = min(a,1)
    float q = fminf(a, 1.0f);
    return 0.5f * q * q + (a - q);
}

// Stage 1: ONE WAVE per batch element (was: one 256-thread block per element).
// Rationale (R3): counters showed latency-bound (VALUBusy 11.7%, HBM 16.5%,
// both low). Per-thread ILP was 10 float4 loads followed by a cross-wave LDS
// reduction + __syncthreads + serial tid==0 tail. Wave-per-element gives each
// lane 40 independent float4 loads, wave-only shuffle reduction (no LDS, no
// barrier), and 4 concurrent epilogues per block.
__global__ __launch_bounds__(BLOCK, 4) void loss_stage1(
    const float* __restrict__ mask_xyz_mean,    // (B,3)
    const float* __restrict__ point_cloud,      // (B,3,N)
    const float* __restrict__ x_delta,          // (B,3,N)
    const float* __restrict__ center_label,     // (B,3)
    const float* __restrict__ size_residual,    // (B,3)
    const float* __restrict__ heading_residual, // (B,)
    const float* __restrict__ mean_sizes,       // (8,3)
    const int*   __restrict__ size_class,       // (B,)
    const int*   __restrict__ heading_class,    // (B,)
    float* __restrict__ ws)                     // (B,) per-element totals
{
    const int wave = threadIdx.x >> 6;
    const int lane = threadIdx.x & 63;
    const int b    = blockIdx.x * WPB + wave;

    // Wave-uniform scalars (same-address broadcast loads within the wave)
    const float cx = center_label[b * 3 + 0];
    const float cy = center_label[b * 3 + 1];

    const float vnorm2 = cx * cx + cy * cy;
    const float vnorm  = sqrtf(vnorm2);
    const float pdx = -cy / vnorm;
    const float pdy =  cx / vnorm;

    const size_t base = (size_t)b * 3 * N_PTS;
    const float4* px4 = (const float4*)(point_cloud + base);            // row 0 (x)
    const float4* py4 = (const float4*)(point_cloud + base + N_PTS);    // row 1 (y)
    const float4* pd4 = (const float4*)(x_delta + base);                // 3*N contiguous

    float s_pp = 0.f, s_pp2 = 0.f, s_t = 0.f, s_t2 = 0.f, s_d2 = 0.f;

    // pc rows 0/1: 512 float4 each -> 8 per lane per row
    #pragma unroll
    for (int k = 0; k < N_PTS / 4 / 64; ++k) {   // 8 iterations
        const int i = lane + k * 64;
        const float4 x4 = px4[i];
        const float4 y4 = py4[i];
        {
            float pp = x4.x * pdx + y4.x * pdy;
            float t  = x4.x * cx  + y4.x * cy;
            s_pp += pp; s_pp2 += pp * pp; s_t += t; s_t2 += t * t;
        }
        {
            float pp = x4.y * pdx + y4.y * pdy;
            float t  = x4.y * cx  + y4.y * cy;
            s_pp += pp; s_pp2 += pp * pp; s_t += t; s_t2 += t * t;
        }
        {
            float pp = x4.z * pdx + y4.z * pdy;
            float t  = x4.z * cx  + y4.z * cy;
            s_pp += pp; s_pp2 += pp * pp; s_t += t; s_t2 += t * t;
        }
        {
            float pp = x4.w * pdx + y4.w * pdy;
            float t  = x4.w * cx  + y4.w * cy;
            s_pp += pp; s_pp2 += pp * pp; s_t += t; s_t2 += t * t;
        }
    }

    // x_delta: 1536 float4 -> 24 per lane
    #pragma unroll
    for (int k = 0; k < 3 * N_PTS / 4 / 64; ++k) {   // 24 iterations
        const float4 d = pd4[lane + k * 64];
        s_d2 += d.x * d.x + d.y * d.y + d.z * d.z + d.w * d.w;
    }

    // wave(64) shuffle reduction — the ONLY reduction needed now
    #pragma unroll
    for (int off = 32; off > 0; off >>= 1) {
        s_pp  += __shfl_down(s_pp,  off, 64);
        s_pp2 += __shfl_down(s_pp2, off, 64);
        s_t   += __shfl_down(s_t,   off, 64);
        s_t2  += __shfl_down(s_t2,  off, 64);
        s_d2  += __shfl_down(s_d2,  off, 64);
    }

    if (lane == 0) {
        // --- label-side scalar math (one lane per wave; 4 run concurrently) ---
        const float mx = mask_xyz_mean[b * 3 + 0];
        const float my = mask_xyz_mean[b * 3 + 1];
        const float mz = mask_xyz_mean[b * 3 + 2];
        const float cz = center_label[b * 3 + 2];
        const float dxc = mx - cx, dyc = my - cy, dzc = mz - cz;
        const float center_dist = sqrtf(dxc * dxc + dyc * dyc + dzc * dzc);

        const int sc = size_class[b];
        const float l  = mean_sizes[sc * 3 + 0] + size_residual[b * 3 + 0];
        const float w_ = mean_sizes[sc * 3 + 1] + size_residual[b * 3 + 1];
        // h (size z) does not affect the 2D corners used below

        const float theta = heading_residual[b] +
                            (float)heading_class[b] * (float)(M_PI / 12.0);
        const float c = cosf(theta);
        const float s = sinf(theta);
        const float hl = 0.5f * l, hw = 0.5f * w_;

        // bottom corners k=4..7: sx={1,1,-1,-1}, sy={1,-1,-1,1}
        float X[4], Y[4];
        X[0] =  c * hl - s * hw + cx;  Y[0] =  s * hl + c * hw + cy;
        X[1] =  c * hl + s * hw + cx;  Y[1] =  s * hl - c * hw + cy;
        X[2] = -c * hl + s * hw + cx;  Y[2] = -s * hl - c * hw + cy;
        X[3] = -c * hl - s * hw + cx;  Y[3] = -s * hl + c * hw + cy;

        float ppmax = -INFINITY, ppmin = INFINITY;
        float pmax  = -INFINITY, pmin  = INFINITY;
        #pragma unroll
        for (int k = 0; k < 4; ++k) {
            const float pp = X[k] * pdx + Y[k] * pdy;
            const float pj = (X[k] * cx + Y[k] * cy) / vnorm;
            ppmax = fmaxf(ppmax, pp); ppmin = fminf(ppmin, pp);
            pmax  = fmaxf(pmax,  pj); pmin  = fminf(pmin,  pj);
        }
        const float std_y_label  = (ppmax - ppmin) * 0.25f;
        const float mean_y_label = (ppmax + ppmin) * 0.5f;
        const float std_label    = (pmax - pmin) * 0.25f;
        const float mean_label   = (pmax + pmin) * 0.5f;

        // --- point-cloud stats (ddof=1) ---
        const float invN   = 1.0f / (float)N_PTS;
        const float invNm1 = 1.0f / (float)(N_PTS - 1);

        const float mean_y_pc = s_pp * invN;
        const float var_y = (s_pp2 - s_pp * s_pp * invN) * invNm1;
        const float std_y_pc = sqrtf(fmaxf(var_y, 0.0f));

        const float mean_pc = (s_t * invN) / vnorm;
        const float var_x = ((s_t2 - s_t * s_t * invN) * invNm1) / vnorm2;
        const float std_pc = sqrtf(fmaxf(var_x, 0.0f));

        const float delta_norm = sqrtf(s_d2);

        const float total =
              0.5f  * huber1(center_dist)
            +         huber1(fabsf(std_label  - std_pc))
            +         huber1(fabsf(mean_label - mean_pc))
            + 0.01f * huber1(delta_norm)
            +         huber1(fabsf(mean_y_label - mean_y_pc))
            +         huber1(fabsf(std_y_label  - std_y_pc));

        ws[b] = total;   // plain store — no contention
    }
}

// Stage 2: single block reduces the 4096 per-element totals.
__global__ __launch_bounds__(BLOCK) void loss_stage2(
    const float* __restrict__ ws, float* __restrict__ out)
{
    const int tid = threadIdx.x;
    const float4* w4 = (const float4*)ws;   // 1024 float4 -> 4 per thread

    float s = 0.f;
    #pragma unroll
    for (int k = 0; k < B_SZ / 4 / BLOCK; ++k) {
        const float4 v = w4[tid + k * BLOCK];
        s += v.x + v.y + v.z + v.w;
    }

    #pragma unroll
    for (int off = 32; off > 0; off >>= 1)
        s += __shfl_down(s, off, 64);

    __shared__ float red[BLOCK / 64];
    const int wave = tid >> 6;
    const int lane = tid & 63;
    if (lane == 0) red[wave] = s;
    __syncthreads();

    if (tid == 0) {
        #pragma unroll
        for (int w = 1; w < BLOCK / 64; ++w) s += red[w];
        out[0] = s * (0.4f / (float)B_SZ);
    }
}

extern "C" void kernel_launch(void* const* d_in, const int* in_sizes, int n_in,
                              void* d_out, int out_size, void* d_ws, size_t ws_size,
                              hipStream_t stream) {
    const float* mask_xyz_mean    = (const float*)d_in[0];
    const float* point_cloud      = (const float*)d_in[1];
    const float* x_delta          = (const float*)d_in[2];
    const float* center_label     = (const float*)d_in[3];
    const float* size_residual    = (const float*)d_in[4];
    const float* heading_residual = (const float*)d_in[5];
    const float* mean_sizes       = (const float*)d_in[6];
    const int*   size_class       = (const int*)d_in[7];
    const int*   heading_class    = (const int*)d_in[8];
    float* ws  = (float*)d_ws;    // 4096 floats = 16 KB scratch
    float* out = (float*)d_out;

    loss_stage1<<<B_SZ / WPB, BLOCK, 0, stream>>>(
        mask_xyz_mean, point_cloud, x_delta, center_label, size_residual,
        heading_residual, mean_sizes, size_class, heading_class, ws);
    loss_stage2<<<1, BLOCK, 0, stream>>>(ws, out);
}

// Round 2
// 223.866 us; speedup vs baseline: 1.0064x; 1.0064x over previous
//
#include <hip/hip_runtime.h>
#include <math.h>

#define B_SZ 4096
#define N_PTS 2048
#define BLOCK 256

__device__ __forceinline__ float huber1(float a) {
    // a >= 0, delta = 1: 0.5*q*q + (a - q), q = min(a,1)
    float q = fminf(a, 1.0f);
    return 0.5f * q * q + (a - q);
}

// ---------------------------------------------------------------------------
// R2 rationale: R0 (32 waves/CU, shallow loads) and R1 (16 waves/CU, deep
// loads) both hit the same 2.5 TB/s effective read rate -> the limiter is
// invariant to occupancy and per-wave load COUNT. Hypothesis: the compiler
// never keeps many loads in flight (load->FMA interleave with tight vmcnt
// waits). Fix: load-ALL-then-consume bursts with static-indexed float4
// arrays, forcing 4-6 KB in flight per wave by construction. Also split the
// two independent streams (point_cloud rows / x_delta) into separate pure
// streaming kernels so rocprof reports per-stream BW.
// ---------------------------------------------------------------------------

// Kernel 1: point-cloud projections. One block per element. 67 MB stream.
// Writes 4 partial-sum planes to ws[j*B + b], j = 0..3 (pp, pp2, t, t2).
__global__ __launch_bounds__(BLOCK, 8) void pc_stats(
    const float* __restrict__ point_cloud,      // (B,3,N)
    const float* __restrict__ center_label,     // (B,3)
    float* __restrict__ ws)
{
    const int b   = blockIdx.x;
    const int tid = threadIdx.x;

    // Block-uniform scalars
    const float cx = center_label[b * 3 + 0];
    const float cy = center_label[b * 3 + 1];
    const float vnorm = sqrtf(cx * cx + cy * cy);
    const float pdx = -cy / vnorm;
    const float pdy =  cx / vnorm;

    const size_t base = (size_t)b * 3 * N_PTS;
    const float4* px4 = (const float4*)(point_cloud + base);          // row 0 (x)
    const float4* py4 = (const float4*)(point_cloud + base + N_PTS);  // row 1 (y)

    // ---- burst ALL loads before any consumption (16 VGPRs of dest) ----
    const float4 vx0 = px4[tid];
    const float4 vx1 = px4[tid + BLOCK];
    const float4 vy0 = py4[tid];
    const float4 vy1 = py4[tid + BLOCK];

    float s_pp = 0.f, s_pp2 = 0.f, s_t = 0.f, s_t2 = 0.f;
    {
        const float xs[8] = {vx0.x, vx0.y, vx0.z, vx0.w, vx1.x, vx1.y, vx1.z, vx1.w};
        const float ys[8] = {vy0.x, vy0.y, vy0.z, vy0.w, vy1.x, vy1.y, vy1.z, vy1.w};
        #pragma unroll
        for (int j = 0; j < 8; ++j) {
            const float pp = xs[j] * pdx + ys[j] * pdy;
            const float t  = xs[j] * cx  + ys[j] * cy;
            s_pp += pp; s_pp2 += pp * pp; s_t += t; s_t2 += t * t;
        }
    }

    // wave(64) shuffle reduction
    #pragma unroll
    for (int off = 32; off > 0; off >>= 1) {
        s_pp  += __shfl_down(s_pp,  off, 64);
        s_pp2 += __shfl_down(s_pp2, off, 64);
        s_t   += __shfl_down(s_t,   off, 64);
        s_t2  += __shfl_down(s_t2,  off, 64);
    }

    __shared__ float red[BLOCK / 64][4];
    const int wave = tid >> 6;
    const int lane = tid & 63;
    if (lane == 0) {
        red[wave][0] = s_pp;  red[wave][1] = s_pp2;
        red[wave][2] = s_t;   red[wave][3] = s_t2;
    }
    __syncthreads();

    if (tid == 0) {
        #pragma unroll
        for (int w = 1; w < BLOCK / 64; ++w) {
            s_pp  += red[w][0];
            s_pp2 += red[w][1];
            s_t   += red[w][2];
            s_t2  += red[w][3];
        }
        ws[0 * B_SZ + b] = s_pp;
        ws[1 * B_SZ + b] = s_pp2;
        ws[2 * B_SZ + b] = s_t;
        ws[3 * B_SZ + b] = s_t2;
    }
}

// Kernel 2: x_delta sum-of-squares (101 MB stream) + per-element epilogue.
// One block per element; reads the pc partials written by pc_stats (prior
// kernel on the same stream -> visible). Writes total to ws[4*B + b].
__global__ __launch_bounds__(BLOCK, 8) void xd_epilogue(
    const float* __restrict__ x_delta,          // (B,3,N)
    const float* __restrict__ mask_xyz_mean,    // (B,3)
    const float* __restrict__ center_label,     // (B,3)
    const float* __restrict__ size_residual,    // (B,3)
    const float* __restrict__ heading_residual, // (B,)
    const float* __restrict__ mean_sizes,       // (8,3)
    const int*   __restrict__ size_class,       // (B,)
    const int*   __restrict__ heading_class,    // (B,)
    float* __restrict__ ws)
{
    const int b   = blockIdx.x;
    const int tid = threadIdx.x;

    const float4* pd4 = (const float4*)(x_delta + (size_t)b * 3 * N_PTS);

    // ---- burst ALL 6 loads before any consumption (24 VGPRs of dest) ----
    float4 d[6];
    #pragma unroll
    for (int k = 0; k < 6; ++k)
        d[k] = pd4[tid + k * BLOCK];

    float s_d2 = 0.f;
    #pragma unroll
    for (int k = 0; k < 6; ++k)
        s_d2 += d[k].x * d[k].x + d[k].y * d[k].y + d[k].z * d[k].z + d[k].w * d[k].w;

    #pragma unroll
    for (int off = 32; off > 0; off >>= 1)
        s_d2 += __shfl_down(s_d2, off, 64);

    __shared__ float red[BLOCK / 64];
    const int wave = tid >> 6;
    const int lane = tid & 63;
    if (lane == 0) red[wave] = s_d2;
    __syncthreads();

    if (tid == 0) {
        #pragma unroll
        for (int w = 1; w < BLOCK / 64; ++w) s_d2 += red[w];

        // pc partials from kernel 1
        const float s_pp  = ws[0 * B_SZ + b];
        const float s_pp2 = ws[1 * B_SZ + b];
        const float s_t   = ws[2 * B_SZ + b];
        const float s_t2  = ws[3 * B_SZ + b];

        // --- label-side scalar math ---
        const float cx = center_label[b * 3 + 0];
        const float cy = center_label[b * 3 + 1];
        const float cz = center_label[b * 3 + 2];
        const float vnorm2 = cx * cx + cy * cy;
        const float vnorm  = sqrtf(vnorm2);
        const float pdx = -cy / vnorm;
        const float pdy =  cx / vnorm;

        const float mx = mask_xyz_mean[b * 3 + 0];
        const float my = mask_xyz_mean[b * 3 + 1];
        const float mz = mask_xyz_mean[b * 3 + 2];
        const float dxc = mx - cx, dyc = my - cy, dzc = mz - cz;
        const float center_dist = sqrtf(dxc * dxc + dyc * dyc + dzc * dzc);

        const int sc = size_class[b];
        const float l  = mean_sizes[sc * 3 + 0] + size_residual[b * 3 + 0];
        const float w_ = mean_sizes[sc * 3 + 1] + size_residual[b * 3 + 1];
        // h (size z) does not affect the 2D corners used below

        const float theta = heading_residual[b] +
                            (float)heading_class[b] * (float)(M_PI / 12.0);
        const float c = cosf(theta);
        const float s = sinf(theta);
        const float hl = 0.5f * l, hw = 0.5f * w_;

        // bottom corners k=4..7: sx={1,1,-1,-1}, sy={1,-1,-1,1}
        float X[4], Y[4];
        X[0] =  c * hl - s * hw + cx;  Y[0] =  s * hl + c * hw + cy;
        X[1] =  c * hl + s * hw + cx;  Y[1] =  s * hl - c * hw + cy;
        X[2] = -c * hl + s * hw + cx;  Y[2] = -s * hl - c * hw + cy;
        X[3] = -c * hl - s * hw + cx;  Y[3] = -s * hl + c * hw + cy;

        float ppmax = -INFINITY, ppmin = INFINITY;
        float pmax  = -INFINITY, pmin  = INFINITY;
        #pragma unroll
        for (int k = 0; k < 4; ++k) {
            const float pp = X[k] * pdx + Y[k] * pdy;
            const float pj = (X[k] * cx + Y[k] * cy) / vnorm;
            ppmax = fmaxf(ppmax, pp); ppmin = fminf(ppmin, pp);
            pmax  = fmaxf(pmax,  pj); pmin  = fminf(pmin,  pj);
        }
        const float std_y_label  = (ppmax - ppmin) * 0.25f;
        const float mean_y_label = (ppmax + ppmin) * 0.5f;
        const float std_label    = (pmax - pmin) * 0.25f;
        const float mean_label   = (pmax + pmin) * 0.5f;

        // --- point-cloud stats (ddof=1) ---
        const float invN   = 1.0f / (float)N_PTS;
        const float invNm1 = 1.0f / (float)(N_PTS - 1);

        const float mean_y_pc = s_pp * invN;
        const float var_y = (s_pp2 - s_pp * s_pp * invN) * invNm1;
        const float std_y_pc = sqrtf(fmaxf(var_y, 0.0f));

        const float mean_pc = (s_t * invN) / vnorm;
        const float var_x = ((s_t2 - s_t * s_t * invN) * invNm1) / vnorm2;
        const float std_pc = sqrtf(fmaxf(var_x, 0.0f));

        const float delta_norm = sqrtf(s_d2);

        const float total =
              0.5f  * huber1(center_dist)
            +         huber1(fabsf(std_label  - std_pc))
            +         huber1(fabsf(mean_label - mean_pc))
            + 0.01f * huber1(delta_norm)
            +         huber1(fabsf(mean_y_label - mean_y_pc))
            +         huber1(fabsf(std_y_label  - std_y_pc));

        ws[4 * B_SZ + b] = total;   // plain store — no contention
    }
}

// Kernel 3: single block reduces the 4096 per-element totals.
__global__ __launch_bounds__(BLOCK) void loss_reduce(
    const float* __restrict__ ws, float* __restrict__ out)
{
    const int tid = threadIdx.x;
    const float4* w4 = (const float4*)(ws + 4 * B_SZ);   // 1024 float4

    float s = 0.f;
    #pragma unroll
    for (int k = 0; k < B_SZ / 4 / BLOCK; ++k) {
        const float4 v = w4[tid + k * BLOCK];
        s += v.x + v.y + v.z + v.w;
    }

    #pragma unroll
    for (int off = 32; off > 0; off >>= 1)
        s += __shfl_down(s, off, 64);

    __shared__ float red[BLOCK / 64];
    const int wave = tid >> 6;
    const int lane = tid & 63;
    if (lane == 0) red[wave] = s;
    __syncthreads();

    if (tid == 0) {
        #pragma unroll
        for (int w = 1; w < BLOCK / 64; ++w) s += red[w];
        out[0] = s * (0.4f / (float)B_SZ);
    }
}

extern "C" void kernel_launch(void* const* d_in, const int* in_sizes, int n_in,
                              void* d_out, int out_size, void* d_ws, size_t ws_size,
                              hipStream_t stream) {
    const float* mask_xyz_mean    = (const float*)d_in[0];
    const float* point_cloud      = (const float*)d_in[1];
    const float* x_delta          = (const float*)d_in[2];
    const float* center_label     = (const float*)d_in[3];
    const float* size_residual    = (const float*)d_in[4];
    const float* heading_residual = (const float*)d_in[5];
    const float* mean_sizes       = (const float*)d_in[6];
    const int*   size_class       = (const int*)d_in[7];
    const int*   heading_class    = (const int*)d_in[8];
    float* ws  = (float*)d_ws;    // 5 planes of 4096 floats = 80 KB scratch
    float* out = (float*)d_out;

    pc_stats<<<B_SZ, BLOCK, 0, stream>>>(point_cloud, center_label, ws);
    xd_epilogue<<<B_SZ, BLOCK, 0, stream>>>(
        x_delta, mask_xyz_mean, center_label, size_residual,
        heading_residual, mean_sizes, size_class, heading_class, ws);
    loss_reduce<<<1, BLOCK, 0, stream>>>(ws, out);
}

// Round 3
// 223.806 us; speedup vs baseline: 1.0067x; 1.0003x over previous
//
#include <hip/hip_runtime.h>
#include <math.h>

#define B_SZ 4096
#define N_PTS 2048
#define BLOCK 256
#define SWEEP_BLOCKS 2048   // blocks per stream-sweep
#define XD_ITERS 12         // 24576 xd windows / 2048 blocks
#define PC_ITERS 4          // 8192 pc x-windows / 2048 blocks

// ws layout (floats):
//   [WS_PC,  +131072)  pc per-wave partials: float4{pp,pp2,t,t2} per (window*4+wave)
//   [WS_XD,  +98304)   xd per-wave partials: float per (window*4+wave)
//   [WS_TOT, +4096)    per-element totals
// total ~950 KB (the harness workspace is the 384 MiB buffer the fills poison).
#define WS_PC  0
#define WS_XD  131072
#define WS_TOT (131072 + 98304)

__device__ __forceinline__ float huber1(float a) {
    // a >= 0, delta = 1: 0.5*q*q + (a - q), q = min(a,1)
    float q = fminf(a, 1.0f);
    return 0.5f * q * q + (a - q);
}

// ---------------------------------------------------------------------------
// R3 rationale: three structurally different per-element kernels (R0 shallow/
// block, R1 deep/wave, R2 burst/block) ALL hit ~2.5 TB/s effective read —
// invariant to occupancy and load depth. Shared property: ~2048 resident
// blocks each streaming a private 16-24 KB slab -> instantaneous address
// footprint spans the whole 200 MB (bank/page thrash). The harness fill and
// float4-copy ubench (6.9 / 6.3 TB/s) sweep memory in lockstep instead.
// This kernel mimics the sweep: grid-stride 1KB/thread windows, consecutive
// blocks on consecutive addresses, whole grid advancing together. A window
// (256 float4) sits inside one element, so element is block-uniform per
// iteration -> one wave-shuffle reduce + per-wave partial store per iter
// (no atomics, no barriers, deterministic).
// ---------------------------------------------------------------------------
__global__ __launch_bounds__(BLOCK, 8) void sweep(
    const float* __restrict__ point_cloud,      // (B,3,N)
    const float* __restrict__ x_delta,          // (B,3,N)
    const float* __restrict__ center_label,     // (B,3)
    float* __restrict__ ws)
{
    const int tid  = threadIdx.x;
    const int wave = tid >> 6;
    const int lane = tid & 63;

    if (blockIdx.x < SWEEP_BLOCKS) {
        // ---- x_delta sweep: 100 MB, fully contiguous ----
        const int s = blockIdx.x;
        const float4* xd4 = (const float4*)x_delta;
        float* __restrict__ wxd = ws + WS_XD;
        #pragma unroll
        for (int k = 0; k < XD_ITERS; ++k) {
            const int W = s + k * SWEEP_BLOCKS;              // window id [0,24576)
            const float4 d = xd4[(size_t)W * 256 + tid];
            float v = d.x * d.x + d.y * d.y + d.z * d.z + d.w * d.w;
            #pragma unroll
            for (int off = 32; off > 0; off >>= 1)
                v += __shfl_down(v, off, 64);
            if (lane == 0) wxd[W * 4 + wave] = v;
        }
    } else {
        // ---- point-cloud rows 0/1 sweep: two interleaved windows 8 KB apart ----
        const int s = blockIdx.x - SWEEP_BLOCKS;
        const float4* pc4 = (const float4*)point_cloud;
        float4* __restrict__ wpc = (float4*)(ws + WS_PC);
        #pragma unroll
        for (int k = 0; k < PC_ITERS; ++k) {
            const int W = s + k * SWEEP_BLOCKS;              // x-window id [0,8192)
            const int e = W >> 1;                            // element (block-uniform)
            const int h = W & 1;                             // which half of the row
            const float cx = center_label[e * 3 + 0];        // broadcast loads
            const float cy = center_label[e * 3 + 1];
            const float vn  = sqrtf(cx * cx + cy * cy);
            const float pdx = -cy / vn;
            const float pdy =  cx / vn;

            const size_t fx = (size_t)e * 1536 + h * 256 + tid;  // float4 index
            const float4 x4 = pc4[fx];
            const float4 y4 = pc4[fx + 512];                 // matching y row

            float s_pp = 0.f, s_pp2 = 0.f, s_t = 0.f, s_t2 = 0.f;
            {
                const float xs[4] = {x4.x, x4.y, x4.z, x4.w};
                const float ys[4] = {y4.x, y4.y, y4.z, y4.w};
                #pragma unroll
                for (int j = 0; j < 4; ++j) {
                    const float pp = xs[j] * pdx + ys[j] * pdy;
                    const float t  = xs[j] * cx  + ys[j] * cy;
                    s_pp += pp; s_pp2 += pp * pp; s_t += t; s_t2 += t * t;
                }
            }
            #pragma unroll
            for (int off = 32; off > 0; off >>= 1) {
                s_pp  += __shfl_down(s_pp,  off, 64);
                s_pp2 += __shfl_down(s_pp2, off, 64);
                s_t   += __shfl_down(s_t,   off, 64);
                s_t2  += __shfl_down(s_t2,  off, 64);
            }
            if (lane == 0)
                wpc[W * 4 + wave] = make_float4(s_pp, s_pp2, s_t, s_t2);
        }
    }
}

// Finalize: one thread per element (epilogue now 4096-way parallel, was
// lane-0-serial). Gathers 8 pc-partial float4s + 6 xd-partial float4s.
__global__ __launch_bounds__(BLOCK) void finalize(
    const float* __restrict__ mask_xyz_mean,    // (B,3)
    const float* __restrict__ center_label,     // (B,3)
    const float* __restrict__ size_residual,    // (B,3)
    const float* __restrict__ heading_residual, // (B,)
    const float* __restrict__ mean_sizes,       // (8,3)
    const int*   __restrict__ size_class,       // (B,)
    const int*   __restrict__ heading_class,    // (B,)
    float* __restrict__ ws)
{
    const int e = blockIdx.x * BLOCK + threadIdx.x;   // [0, 4096)

    // pc partials: element e owns windows 2e,2e+1 x 4 waves = 8 contiguous float4
    float s_pp = 0.f, s_pp2 = 0.f, s_t = 0.f, s_t2 = 0.f;
    const float4* pcp = ((const float4*)(ws + WS_PC)) + (size_t)e * 8;
    #pragma unroll
    for (int i = 0; i < 8; ++i) {
        const float4 p = pcp[i];
        s_pp += p.x; s_pp2 += p.y; s_t += p.z; s_t2 += p.w;
    }
    // xd partials: element e owns windows 6e..6e+5 x 4 waves = 24 contiguous floats
    float s_d2 = 0.f;
    const float4* xdp = ((const float4*)(ws + WS_XD)) + (size_t)e * 6;
    #pragma unroll
    for (int i = 0; i < 6; ++i) {
        const float4 p = xdp[i];
        s_d2 += (p.x + p.y) + (p.z + p.w);
    }

    // --- label-side scalar math (identical to verified R2 epilogue) ---
    const float cx = center_label[e * 3 + 0];
    const float cy = center_label[e * 3 + 1];
    const float cz = center_label[e * 3 + 2];
    const float vnorm2 = cx * cx + cy * cy;
    const float vnorm  = sqrtf(vnorm2);
    const float pdx = -cy / vnorm;
    const float pdy =  cx / vnorm;

    const float mx = mask_xyz_mean[e * 3 + 0];
    const float my = mask_xyz_mean[e * 3 + 1];
    const float mz = mask_xyz_mean[e * 3 + 2];
    const float dxc = mx - cx, dyc = my - cy, dzc = mz - cz;
    const float center_dist = sqrtf(dxc * dxc + dyc * dyc + dzc * dzc);

    const int sc = size_class[e];
    const float l  = mean_sizes[sc * 3 + 0] + size_residual[e * 3 + 0];
    const float w_ = mean_sizes[sc * 3 + 1] + size_residual[e * 3 + 1];
    // h (size z) does not affect the 2D corners used below

    const float theta = heading_residual[e] +
                        (float)heading_class[e] * (float)(M_PI / 12.0);
    const float c = cosf(theta);
    const float s = sinf(theta);
    const float hl = 0.5f * l, hw = 0.5f * w_;

    // bottom corners k=4..7: sx={1,1,-1,-1}, sy={1,-1,-1,1}
    float X[4], Y[4];
    X[0] =  c * hl - s * hw + cx;  Y[0] =  s * hl + c * hw + cy;
    X[1] =  c * hl + s * hw + cx;  Y[1] =  s * hl - c * hw + cy;
    X[2] = -c * hl + s * hw + cx;  Y[2] = -s * hl - c * hw + cy;
    X[3] = -c * hl - s * hw + cx;  Y[3] = -s * hl + c * hw + cy;

    float ppmax = -INFINITY, ppmin = INFINITY;
    float pmax  = -INFINITY, pmin  = INFINITY;
    #pragma unroll
    for (int k = 0; k < 4; ++k) {
        const float pp = X[k] * pdx + Y[k] * pdy;
        const float pj = (X[k] * cx + Y[k] * cy) / vnorm;
        ppmax = fmaxf(ppmax, pp); ppmin = fminf(ppmin, pp);
        pmax  = fmaxf(pmax,  pj); pmin  = fminf(pmin,  pj);
    }
    const float std_y_label  = (ppmax - ppmin) * 0.25f;
    const float mean_y_label = (ppmax + ppmin) * 0.5f;
    const float std_label    = (pmax - pmin) * 0.25f;
    const float mean_label   = (pmax + pmin) * 0.5f;

    // --- point-cloud stats (ddof=1) ---
    const float invN   = 1.0f / (float)N_PTS;
    const float invNm1 = 1.0f / (float)(N_PTS - 1);

    const float mean_y_pc = s_pp * invN;
    const float var_y = (s_pp2 - s_pp * s_pp * invN) * invNm1;
    const float std_y_pc = sqrtf(fmaxf(var_y, 0.0f));

    const float mean_pc = (s_t * invN) / vnorm;
    const float var_x = ((s_t2 - s_t * s_t * invN) * invNm1) / vnorm2;
    const float std_pc = sqrtf(fmaxf(var_x, 0.0f));

    const float delta_norm = sqrtf(s_d2);

    const float total =
          0.5f  * huber1(center_dist)
        +         huber1(fabsf(std_label  - std_pc))
        +         huber1(fabsf(mean_label - mean_pc))
        + 0.01f * huber1(delta_norm)
        +         huber1(fabsf(mean_y_label - mean_y_pc))
        +         huber1(fabsf(std_y_label  - std_y_pc));

    ws[WS_TOT + e] = total;
}

// Final reduce: single block sums the 4096 per-element totals.
__global__ __launch_bounds__(BLOCK) void loss_reduce(
    const float* __restrict__ ws, float* __restrict__ out)
{
    const int tid = threadIdx.x;
    const float4* w4 = (const float4*)(ws + WS_TOT);   // 1024 float4

    float s = 0.f;
    #pragma unroll
    for (int k = 0; k < B_SZ / 4 / BLOCK; ++k) {
        const float4 v = w4[tid + k * BLOCK];
        s += v.x + v.y + v.z + v.w;
    }

    #pragma unroll
    for (int off = 32; off > 0; off >>= 1)
        s += __shfl_down(s, off, 64);

    __shared__ float red[BLOCK / 64];
    const int wave = tid >> 6;
    const int lane = tid & 63;
    if (lane == 0) red[wave] = s;
    __syncthreads();

    if (tid == 0) {
        #pragma unroll
        for (int w = 1; w < BLOCK / 64; ++w) s += red[w];
        out[0] = s * (0.4f / (float)B_SZ);
    }
}

extern "C" void kernel_launch(void* const* d_in, const int* in_sizes, int n_in,
                              void* d_out, int out_size, void* d_ws, size_t ws_size,
                              hipStream_t stream) {
    const float* mask_xyz_mean    = (const float*)d_in[0];
    const float* point_cloud      = (const float*)d_in[1];
    const float* x_delta          = (const float*)d_in[2];
    const float* center_label     = (const float*)d_in[3];
    const float* size_residual    = (const float*)d_in[4];
    const float* heading_residual = (const float*)d_in[5];
    const float* mean_sizes       = (const float*)d_in[6];
    const int*   size_class       = (const int*)d_in[7];
    const int*   heading_class    = (const int*)d_in[8];
    float* ws  = (float*)d_ws;    // ~950 KB used
    float* out = (float*)d_out;

    // blocks 0..2047: x_delta sweep (bigger stream, dispatched first)
    // blocks 2048..4095: point-cloud sweep
    sweep<<<2 * SWEEP_BLOCKS, BLOCK, 0, stream>>>(
        point_cloud, x_delta, center_label, ws);
    finalize<<<B_SZ / BLOCK, BLOCK, 0, stream>>>(
        mask_xyz_mean, center_label, size_residual, heading_residual,
        mean_sizes, size_class, heading_class, ws);
    loss_reduce<<<1, BLOCK, 0, stream>>>(ws, out);
}

// Round 5
// 207.069 us; speedup vs baseline: 1.0881x; 1.0808x over previous
//
#include <hip/hip_runtime.h>
#include <math.h>

#define B_SZ 4096
#define N_PTS 2048
#define BLOCK 256

// 16-byte vector type usable with __builtin_nontemporal_load
typedef float f4 __attribute__((ext_vector_type(4)));

// ws float layout:
//   WS_PC  : per-element per-wave pc partials {pp,pp2,t,t2} : 4096*4 f4
//   WS_XD  : per-element per-wave xd partials               : 4096*4 floats
//   WS_TOT : per-element totals                             : 4096 floats
#define WS_PC   0
#define WS_XD   65536
#define WS_TOT  (65536 + 16384)

__device__ __forceinline__ float huber1(float a) {
    // a >= 0, delta = 1: 0.5*q*q + (a - q), q = min(a,1)
    float q = fminf(a, 1.0f);
    return 0.5f * q * q + (a - q);
}

// ---------------------------------------------------------------------------
// R5 = R4 experiment, tripwire removed. R4's container failure may have been
// the cross-kernel arrival counter (stateful across rocprof replays) — gone;
// back to the stateless 3-kernel chain proven in R0-R3.
// Theory under test (unchanged): five structure variants all read at
// 2.6-2.7 TB/s while fills write at 6.9 TB/s -> read-path wall (allocation/
// MSHR dwell), so non-temporal loads (skip L2/L3 allocation; data is read
// once per dispatch) are the lever. FETCH_SIZE is the diagnostic: if NT
// destroys the ~50% L3-hit residency (82->~165 MB) and time regresses, L3
// latency was load-bearing and ~2.7 TB/s is the practical read roofline.
// ---------------------------------------------------------------------------
__global__ __launch_bounds__(BLOCK, 8) void sweep(
    const float* __restrict__ point_cloud,      // (B,3,N)
    const float* __restrict__ x_delta,          // (B,3,N)
    const float* __restrict__ center_label,     // (B,3)
    float* __restrict__ ws)
{
    const int tid  = threadIdx.x;
    const int wave = tid >> 6;
    const int lane = tid & 63;

    if (blockIdx.x < (B_SZ / 2)) {
        // ---- x_delta: block owns elements {2s, 2s+1}, 1536 f4 each ----
        const int s = blockIdx.x;
        const f4* xd4 = (const f4*)x_delta;
        #pragma unroll
        for (int e2 = 0; e2 < 2; ++e2) {
            const int e = 2 * s + e2;
            const f4* p = xd4 + (size_t)e * 1536;
            // 6 independent NT loads in flight before any consumption
            const f4 d0 = __builtin_nontemporal_load(p + 0 * BLOCK + tid);
            const f4 d1 = __builtin_nontemporal_load(p + 1 * BLOCK + tid);
            const f4 d2 = __builtin_nontemporal_load(p + 2 * BLOCK + tid);
            const f4 d3 = __builtin_nontemporal_load(p + 3 * BLOCK + tid);
            const f4 d4 = __builtin_nontemporal_load(p + 4 * BLOCK + tid);
            const f4 d5 = __builtin_nontemporal_load(p + 5 * BLOCK + tid);

            float v = 0.f;
            v += d0[0]*d0[0] + d0[1]*d0[1] + d0[2]*d0[2] + d0[3]*d0[3];
            v += d1[0]*d1[0] + d1[1]*d1[1] + d1[2]*d1[2] + d1[3]*d1[3];
            v += d2[0]*d2[0] + d2[1]*d2[1] + d2[2]*d2[2] + d2[3]*d2[3];
            v += d3[0]*d3[0] + d3[1]*d3[1] + d3[2]*d3[2] + d3[3]*d3[3];
            v += d4[0]*d4[0] + d4[1]*d4[1] + d4[2]*d4[2] + d4[3]*d4[3];
            v += d5[0]*d5[0] + d5[1]*d5[1] + d5[2]*d5[2] + d5[3]*d5[3];

            #pragma unroll
            for (int off = 32; off > 0; off >>= 1)
                v += __shfl_down(v, off, 64);
            if (lane == 0) ws[WS_XD + e * 4 + wave] = v;
        }
    } else {
        // ---- point-cloud rows 0/1: block owns elements {2s, 2s+1} ----
        const int s = blockIdx.x - (B_SZ / 2);
        const f4* pc4 = (const f4*)point_cloud;
        f4* __restrict__ wpc = (f4*)(ws + WS_PC);
        #pragma unroll
        for (int e2 = 0; e2 < 2; ++e2) {
            const int e = 2 * s + e2;
            const float cx = center_label[e * 3 + 0];   // block-uniform broadcast
            const float cy = center_label[e * 3 + 1];
            const float vn  = sqrtf(cx * cx + cy * cy);
            const float pdx = -cy / vn;
            const float pdy =  cx / vn;

            const f4* px = pc4 + (size_t)e * 1536;      // x row: 512 f4
            const f4* py = px + 512;                    // y row
            const f4 x0 = __builtin_nontemporal_load(px + tid);
            const f4 x1 = __builtin_nontemporal_load(px + BLOCK + tid);
            const f4 y0 = __builtin_nontemporal_load(py + tid);
            const f4 y1 = __builtin_nontemporal_load(py + BLOCK + tid);

            float s_pp = 0.f, s_pp2 = 0.f, s_t = 0.f, s_t2 = 0.f;
            {
                const float xs[8] = {x0[0], x0[1], x0[2], x0[3], x1[0], x1[1], x1[2], x1[3]};
                const float ys[8] = {y0[0], y0[1], y0[2], y0[3], y1[0], y1[1], y1[2], y1[3]};
                #pragma unroll
                for (int j = 0; j < 8; ++j) {
                    const float pp = xs[j] * pdx + ys[j] * pdy;
                    const float t  = xs[j] * cx  + ys[j] * cy;
                    s_pp += pp; s_pp2 += pp * pp; s_t += t; s_t2 += t * t;
                }
            }
            #pragma unroll
            for (int off = 32; off > 0; off >>= 1) {
                s_pp  += __shfl_down(s_pp,  off, 64);
                s_pp2 += __shfl_down(s_pp2, off, 64);
                s_t   += __shfl_down(s_t,   off, 64);
                s_t2  += __shfl_down(s_t2,  off, 64);
            }
            if (lane == 0) {
                f4 r; r[0] = s_pp; r[1] = s_pp2; r[2] = s_t; r[3] = s_t2;
                wpc[e * 4 + wave] = r;
            }
        }
    }
}

// Finalize: one thread per element. Gathers 4 pc f4-partials + 4 xd floats,
// runs the (verified) label epilogue, writes per-element total. Stateless.
__global__ __launch_bounds__(BLOCK) void finalize(
    const float* __restrict__ mask_xyz_mean,    // (B,3)
    const float* __restrict__ center_label,     // (B,3)
    const float* __restrict__ size_residual,    // (B,3)
    const float* __restrict__ heading_residual, // (B,)
    const float* __restrict__ mean_sizes,       // (8,3)
    const int*   __restrict__ size_class,       // (B,)
    const int*   __restrict__ heading_class,    // (B,)
    float* __restrict__ ws)
{
    const int e = blockIdx.x * BLOCK + threadIdx.x;   // [0, 4096)

    float s_pp = 0.f, s_pp2 = 0.f, s_t = 0.f, s_t2 = 0.f;
    const f4* pcp = ((const f4*)(ws + WS_PC)) + (size_t)e * 4;
    #pragma unroll
    for (int i = 0; i < 4; ++i) {
        const f4 p = pcp[i];
        s_pp += p[0]; s_pp2 += p[1]; s_t += p[2]; s_t2 += p[3];
    }
    float s_d2 = 0.f;
    #pragma unroll
    for (int i = 0; i < 4; ++i) s_d2 += ws[WS_XD + e * 4 + i];

    // --- label-side scalar math (identical to verified R2/R3 epilogue) ---
    const float cx = center_label[e * 3 + 0];
    const float cy = center_label[e * 3 + 1];
    const float cz = center_label[e * 3 + 2];
    const float vnorm2 = cx * cx + cy * cy;
    const float vnorm  = sqrtf(vnorm2);
    const float pdx = -cy / vnorm;
    const float pdy =  cx / vnorm;

    const float mx = mask_xyz_mean[e * 3 + 0];
    const float my = mask_xyz_mean[e * 3 + 1];
    const float mz = mask_xyz_mean[e * 3 + 2];
    const float dxc = mx - cx, dyc = my - cy, dzc = mz - cz;
    const float center_dist = sqrtf(dxc * dxc + dyc * dyc + dzc * dzc);

    const int sc = size_class[e];
    const float l  = mean_sizes[sc * 3 + 0] + size_residual[e * 3 + 0];
    const float w_ = mean_sizes[sc * 3 + 1] + size_residual[e * 3 + 1];
    // h (size z) does not affect the 2D corners used below

    const float theta = heading_residual[e] +
                        (float)heading_class[e] * (float)(M_PI / 12.0);
    const float c = cosf(theta);
    const float s = sinf(theta);
    const float hl = 0.5f * l, hw = 0.5f * w_;

    // bottom corners k=4..7: sx={1,1,-1,-1}, sy={1,-1,-1,1}
    float X[4], Y[4];
    X[0] =  c * hl - s * hw + cx;  Y[0] =  s * hl + c * hw + cy;
    X[1] =  c * hl + s * hw + cx;  Y[1] =  s * hl - c * hw + cy;
    X[2] = -c * hl + s * hw + cx;  Y[2] = -s * hl - c * hw + cy;
    X[3] = -c * hl - s * hw + cx;  Y[3] = -s * hl + c * hw + cy;

    float ppmax = -INFINITY, ppmin = INFINITY;
    float pmax  = -INFINITY, pmin  = INFINITY;
    #pragma unroll
    for (int k = 0; k < 4; ++k) {
        const float pp = X[k] * pdx + Y[k] * pdy;
        const float pj = (X[k] * cx + Y[k] * cy) / vnorm;
        ppmax = fmaxf(ppmax, pp); ppmin = fminf(ppmin, pp);
        pmax  = fmaxf(pmax,  pj); pmin  = fminf(pmin,  pj);
    }
    const float std_y_label  = (ppmax - ppmin) * 0.25f;
    const float mean_y_label = (ppmax + ppmin) * 0.5f;
    const float std_label    = (pmax - pmin) * 0.25f;
    const float mean_label   = (pmax + pmin) * 0.5f;

    // --- point-cloud stats (ddof=1) ---
    const float invN   = 1.0f / (float)N_PTS;
    const float invNm1 = 1.0f / (float)(N_PTS - 1);

    const float mean_y_pc = s_pp * invN;
    const float var_y = (s_pp2 - s_pp * s_pp * invN) * invNm1;
    const float std_y_pc = sqrtf(fmaxf(var_y, 0.0f));

    const float mean_pc = (s_t * invN) / vnorm;
    const float var_x = ((s_t2 - s_t * s_t * invN) * invNm1) / vnorm2;
    const float std_pc = sqrtf(fmaxf(var_x, 0.0f));

    const float delta_norm = sqrtf(s_d2);

    const float total =
          0.5f  * huber1(center_dist)
        +         huber1(fabsf(std_label  - std_pc))
        +         huber1(fabsf(mean_label - mean_pc))
        + 0.01f * huber1(delta_norm)
        +         huber1(fabsf(mean_y_label - mean_y_pc))
        +         huber1(fabsf(std_y_label  - std_y_pc));

    ws[WS_TOT + e] = total;
}

// Final reduce: single block sums the 4096 per-element totals (fixed order).
__global__ __launch_bounds__(BLOCK) void loss_reduce(
    const float* __restrict__ ws, float* __restrict__ out)
{
    const int tid = threadIdx.x;
    const float4* w4 = (const float4*)(ws + WS_TOT);   // 1024 float4

    float s = 0.f;
    #pragma unroll
    for (int k = 0; k < B_SZ / 4 / BLOCK; ++k) {
        const float4 v = w4[tid + k * BLOCK];
        s += v.x + v.y + v.z + v.w;
    }

    #pragma unroll
    for (int off = 32; off > 0; off >>= 1)
        s += __shfl_down(s, off, 64);

    __shared__ float red[BLOCK / 64];
    const int wave = tid >> 6;
    const int lane = tid & 63;
    if (lane == 0) red[wave] = s;
    __syncthreads();

    if (tid == 0) {
        #pragma unroll
        for (int w = 1; w < BLOCK / 64; ++w) s += red[w];
        out[0] = s * (0.4f / (float)B_SZ);
    }
}

extern "C" void kernel_launch(void* const* d_in, const int* in_sizes, int n_in,
                              void* d_out, int out_size, void* d_ws, size_t ws_size,
                              hipStream_t stream) {
    const float* mask_xyz_mean    = (const float*)d_in[0];
    const float* point_cloud      = (const float*)d_in[1];
    const float* x_delta          = (const float*)d_in[2];
    const float* center_label     = (const float*)d_in[3];
    const float* size_residual    = (const float*)d_in[4];
    const float* heading_residual = (const float*)d_in[5];
    const float* mean_sizes       = (const float*)d_in[6];
    const int*   size_class       = (const int*)d_in[7];
    const int*   heading_class    = (const int*)d_in[8];
    float* ws  = (float*)d_ws;    // ~340 KB used
    float* out = (float*)d_out;

    // blocks 0..2047: x_delta (element pairs); 2048..4095: point-cloud pairs
    sweep<<<B_SZ, BLOCK, 0, stream>>>(point_cloud, x_delta, center_label, ws);
    finalize<<<B_SZ / BLOCK, BLOCK, 0, stream>>>(
        mask_xyz_mean, center_label, size_residual, heading_residual,
        mean_sizes, size_class, heading_class, ws);
    loss_reduce<<<1, BLOCK, 0, stream>>>(ws, out);
}